// Round 17
// baseline (239.477 us; speedup 1.0000x reference)
//
#include <hip/hip_runtime.h>
#include <hip/hip_bf16.h>
#include <math.h>

// ---------------- problem constants ----------------
#define BB 32
#define CIN 128
#define HH 56
#define WW 56
#define COUT 256
#define HW (HH*WW)              // 3136
#define NPIX (BB*HW)            // 100352
#define PH 28
#define PW 28
#define POOL_ELEMS ((long)BB*COUT*PH*PW) // 6,422,528
#define PADH 58
#define PADW 58
#define MSTRIDE 64              // m/v row stride (56 used + 8 junk)
#define ROW_BLOCKS (BB*HH)                    // 1792
#define TOPBOT_BLOCKS (BB*2)                  // 64
#define WPACK_BLOCKS ((9*COUT*CIN)/256)       // 1152

typedef unsigned short u16;
using s16x8  = __attribute__((ext_vector_type(8)))  short;
using s16x4  = __attribute__((ext_vector_type(4)))  short;
using f32x4  = __attribute__((ext_vector_type(4)))  float;
using f32x16 = __attribute__((ext_vector_type(16))) float;

__device__ __forceinline__ float b2f(u16 u){ return __uint_as_float(((unsigned)u)<<16); }
__device__ __forceinline__ u16 f2b(float x){           // RNE f32->bf16
    unsigned u = __float_as_uint(x);
    unsigned r = (u + 0x7fffu + ((u>>16)&1u)) >> 16;
    return (u16)r;
}

__device__ __forceinline__ void gload16(const void* g, void* l){
    __builtin_amdgcn_global_load_lds(
        (const __attribute__((address_space(1))) unsigned int*)g,
        (__attribute__((address_space(3))) unsigned int*)l, 16, 0, 0);
}

// ================= FAST PATH =================

// prep: [0,ROW_BLOCKS): NCHW->padded NHWC bf16 via LDS transpose (+halo cols);
// [ROW_BLOCKS,+TOPBOT): zero pad rows 0/57 (+stats zero); then weight pack for
// 32x32x16 B-frags: BP idx = r*32768 + s*4096 + kq*2048 + co*8 + e, where
// ci = s*16 + kq*8 + e  (s=kstep 0..7, kq=lane>>5 half).
__global__ __launch_bounds__(256) void prep_kernel(
    const float* __restrict__ mean, const float* __restrict__ stdv,
    const float* __restrict__ w,
    u16* __restrict__ mean_pad, u16* __restrict__ std2_pad,
    u16* __restrict__ BP, u16* __restrict__ BP2,
    float* __restrict__ sum_, float* __restrict__ sumsq_)
{
    const int bid = blockIdx.x;
    const int t   = threadIdx.x;

    if (bid < ROW_BLOCKS){
        __shared__ u16 ldsm[56*128];
        __shared__ u16 ldss[56*128];
        const int b = bid / HH;
        const int h = bid - b*HH;
        #pragma unroll
        for (int k=0; k<7; ++k){
            int idx = k*256 + t;
            int c   = idx / 14;
            int f4  = idx - c*14;
            long ga = ((long)(b*CIN + c)*HH + h)*WW + f4*4;
            const f32x4 m4 = *(const f32x4*)(mean + ga);
            const f32x4 s4 = *(const f32x4*)(stdv + ga);
            #pragma unroll
            for (int j=0; j<4; ++j){
                int px = f4*4 + j;
                int ci = px*128 + (c ^ ((px & 15) << 3));
                ldsm[ci] = f2b(m4[j]);
                ldss[ci] = f2b(s4[j] * s4[j]);
            }
        }
        __syncthreads();
        const long rowbase = ((long)(b*PADH + (h+1)))*PADW*CIN;
        #pragma unroll
        for (int k=0; k<4; ++k){
            int slot = k*256 + t;
            int px   = slot >> 4;
            int oct  = slot & 15;
            if (px < 56){
                int ci = px*128 + ((oct ^ (px & 15)) << 3);
                long o = rowbase + (long)(px+1)*CIN + oct*8;
                *(s16x8*)(mean_pad + o) = *(const s16x8*)&ldsm[ci];
                *(s16x8*)(std2_pad + o) = *(const s16x8*)&ldss[ci];
            }
        }
        if (t < 64){
            int buf = t >> 5;
            int ppx = ((t >> 4) & 1) ? 57 : 0;
            int oct = t & 15;
            long o  = rowbase + (long)ppx*CIN + oct*8;
            s16x8 z = (s16x8){0,0,0,0,0,0,0,0};
            *(s16x8*)((buf ? std2_pad : mean_pad) + o) = z;
        }
    } else if (bid < ROW_BLOCKS + TOPBOT_BLOCKS){
        int row = bid - ROW_BLOCKS;
        int b   = row >> 1;
        int ph  = (row & 1) ? (PADH-1) : 0;
        const long rowbase = ((long)(b*PADH + ph))*PADW*CIN;
        s16x8 z = (s16x8){0,0,0,0,0,0,0,0};
        #pragma unroll
        for (int k=0; k<8; ++k){
            int g = k*256 + t;
            if (g < 2*PADW*16){
                int buf = g >= PADW*16;
                int gg  = buf ? g - PADW*16 : g;
                int px  = gg >> 4;
                int oct = gg & 15;
                long o  = rowbase + (long)px*CIN + oct*8;
                *(s16x8*)((buf ? std2_pad : mean_pad) + o) = z;
            }
        }
        if (row == 0){ sum_[t] = 0.f; sumsq_[t] = 0.f; }
    } else {
        // weight pack: tt = r*32768 + s*4096 + kq*2048 + co*8 + e
        int tt = (bid - ROW_BLOCKS - TOPBOT_BLOCKS)*256 + t;   // 0..294911
        int e  = tt & 7;
        int co = (tt >> 3) & 255;
        int kq = (tt >> 11) & 1;
        int s  = (tt >> 12) & 7;
        int r  = tt >> 15;                     // 0..8
        int ci = s*16 + kq*8 + e;
        float v = w[((long)co*CIN + ci)*9 + r];
        BP[tt]  = f2b(v);
        BP2[tt] = f2b(v*v);
    }
}

// implicit-GEMM conv -- TAP-REUSE WINDOW + 32x32x16 MFMA.
// r11-r16 invariant: MFMA-busy ~52us constant, wall ~125us; per-instruction
// stalls dominate. 32x32x16 = 2x FLOP per instruction (8.07 CU-cyc vs 4.85,
// +15% pipe ceiling) and HALF the MFMA + af-read instruction count.
// Block = 2 output rows x 256 co, one path; 8 waves, each 2x64 px x 32 co as
// 4 frags of 32px (single-row; cols 56-63 computed, stored to junk stride
// columns, excluded from stats). A layout: row=lane&31, k=(lane>>5)*8+e.
// B: col=lane&31, same k. D: col=lane&31, row=(reg&3)+8*(reg>>2)+4*(lane>>5).
// m/v stored with row stride 64 (unmasked full-line stores; no RMW blowup).
// LDS: [258 rows][16 slots x 16B]; slot_logical = s*2+kq, stored = ^ (R&15);
// write-side source quad (t&15)^((t>>4)&15)  [rule #21, both sides].
__global__ __launch_bounds__(512,4) void convw_kernel(
    const u16* __restrict__ mean_pad, const u16* __restrict__ std2_pad,
    const u16* __restrict__ BP, const u16* __restrict__ BP2,
    const float* __restrict__ bias,
    u16* __restrict__ m_out, u16* __restrict__ v_out,
    float* __restrict__ sum_, float* __restrict__ sumsq_)
{
    __shared__ u16 lds[33024];   // 66KB: [258][16 x 16B] (rows 256-257 slack)
    const int tid  = threadIdx.x;   // 0..511
    const int lane = tid & 63;
    const int wv   = tid >> 6;      // 0..7

    // XCD-affine decode: 1792 blocks = 8 XCDs x 224; 112 p-tiles x 2 paths each.
    int gid   = blockIdx.x;
    int local = gid >> 3;                       // 0..223
    int p     = (gid & 7)*112 + (local >> 1);   // 0..895
    int path  = local & 1;
    const int b  = p / 28;
    const int h0 = (p - b*28) * 2;

    const u16* __restrict__ Ap = path ? std2_pad : mean_pad;
    const u16* __restrict__ Bp = path ? BP2      : BP;
    u16*       __restrict__ Op = path ? v_out    : m_out;

    // ---- stage window (rows 0..255): 8 issues x 512 threads x 16B
    const int slot_g = (tid & 15) ^ ((tid >> 4) & 15);
    const int wbase  = (b*PADH + h0)*PADW*CIN;
    const int athr   = (tid >> 4)*CIN + slot_g*8;
    #pragma unroll
    for (int i=0; i<8; ++i){
        const int Ci = (i>>1)*(PADW*CIN) + (i&1)*32*CIN;
        gload16(Ap + wbase + Ci + athr, &lds[i*4096 + tid*8]);
    }
    __syncthreads();   // single drain for the whole block

    const int l31 = lane & 31;
    const int kq  = lane >> 5;      // k-half (0,1)

    // B per-lane base (u16): + (r*8+s)*4096 per k-step
    const u16* bpl = Bp + (size_t)(kq*2048 + (wv*32 + l31)*8);

    f32x16 acc[4];
    #pragma unroll
    for (int f=0; f<4; ++f)
      #pragma unroll
      for (int e=0; e<16; ++e) acc[f][e] = 0.f;

    #pragma unroll
    for (int r=0; r<9; ++r){
        const int kh = r/3, kw = r - (r/3)*3;   // compile-time

        // frag base rows: f = fr*2+fc ; R = fr*64 + fc*32 + l31 + kh*64 + kw
        int rowoff[4], t15[4];
        #pragma unroll
        for (int f=0; f<4; ++f){
            int R = (f>>1)*64 + (f&1)*32 + l31 + kh*64 + kw;
            rowoff[f] = R*128;
            t15[f]    = R & 15;
        }

        #pragma unroll
        for (int s=0; s<8; ++s){
            s16x8 bf = *(const s16x8*)(bpl + (size_t)(r*8 + s)*4096);
            s16x8 af[4];
            #pragma unroll
            for (int f=0; f<4; ++f){
                int slot = (s*2 + kq) ^ t15[f];
                af[f] = *(const s16x8*)&lds[rowoff[f] + (slot << 3)];
            }
            __builtin_amdgcn_s_setprio(1);
            #pragma unroll
            for (int f=0; f<4; ++f)
                acc[f] = __builtin_amdgcn_mfma_f32_32x32x16_bf16(af[f], bf, acc[f], 0,0,0);
            __builtin_amdgcn_s_setprio(0);
        }
    }

    // ---- epilogue. D: col(co)=lane&31, row(px)=(reg&3)+8*(reg>>2)+4*kq.
    const int co = wv*32 + l31;
    const float bv = (path == 0) ? bias[co] : 0.f;

    float ssum = 0.f, ssq = 0.f;

    #pragma unroll
    for (int f=0; f<4; ++f){
        const int fr = f>>1, fc = f&1;
        const size_t obase = ((size_t)(b*COUT + co)*HH + (h0+fr))*MSTRIDE;
        #pragma unroll
        for (int g=0; g<4; ++g){
            int w0 = fc*32 + g*8 + 4*kq;
            s16x4 pk;
            #pragma unroll
            for (int rr=0; rr<4; ++rr){
                float vv = acc[f][g*4+rr] + bv;
                pk[rr] = (short)f2b(vv);
                if (w0 + rr < 56){ ssum += vv; ssq += vv*vv; }
            }
            *(s16x4*)(Op + obase + w0) = pk;
        }
    }

    if (path == 0){
        ssum += __shfl_xor(ssum, 32, 64);
        ssq  += __shfl_xor(ssq,  32, 64);
        if (lane < 32){
            atomicAdd(&sum_[wv*32 + lane],   ssum);
            atomicAdd(&sumsq_[wv*32 + lane], ssq);
        }
    }
}

// BN + erf + 2x2 pool -> f32 outputs; m/v row stride = MSTRIDE.
__global__ __launch_bounds__(256) void final_kernel(
        const u16* __restrict__ m, const u16* __restrict__ var,
        const float* __restrict__ sum_, const float* __restrict__ sumsq_,
        const float* __restrict__ gamma, const float* __restrict__ beta,
        float* __restrict__ out){
    int idx4 = blockIdx.x*256 + threadIdx.x;   // < POOL_ELEMS/4
    int wo4 = idx4 % (PW/4); int t = idx4 / (PW/4);
    int ho = t % PH; t /= PH;
    int co = t % COUT; int b = t / COUT;
    float g  = gamma[co];
    float be = beta[co];
    float mu = sum_[co] / (float)NPIX;
    float vr = sumsq_[co] / (float)NPIX - mu*mu;
    float inv = 1.0f / sqrtf(vr + 1e-5f);
    float ag = fabsf(g);
    float us[4] = {0.f,0.f,0.f,0.f}, ss[4] = {0.f,0.f,0.f,0.f};
    #pragma unroll
    for (int dh=0; dh<2; ++dh){
        long base = ((long)(b*COUT+co)*HH + 2*ho+dh)*MSTRIDE + wo4*8;
        const s16x8 vm = *(const s16x8*)&m[base];
        const s16x8 vv = *(const s16x8*)&var[base];
        #pragma unroll
        for (int j=0;j<8;j++){
            float mm = b2f((u16)vm[j]);
            float sdev = sqrtf(b2f((u16)vv[j]) + 1e-12f);
            float uhat = (mm - mu)*inv*g + be;
            float shat = sdev*inv*ag;
            float z = uhat / (shat*1.41421356237f + 1e-12f);
            float u = 0.5f*(1.f + erff(z));
            us[j>>1] += u;
            ss[j>>1] += fmaxf(u*(1.f-u), 1e-12f);
        }
    }
    long ob = ((long)(b*COUT+co)*PH + ho)*PW + wo4*4;
    f32x4 o0, o1;
    #pragma unroll
    for (int k=0;k<4;k++){
        o0[k] = 0.25f*us[k];
        o1[k] = sqrtf(0.25f*ss[k])*0.5f;
    }
    *(f32x4*)(out + ob) = o0;
    *(f32x4*)(out + POOL_ELEMS + ob) = o1;
}

// ================= FALLBACK PATH (round-2 VALU conv, bf16 m/v out) =================

__global__ void wtransf_kernel(const float* __restrict__ w, float* __restrict__ wT){
    int out = blockIdx.x*256 + threadIdx.x;
    if (out >= COUT*CIN*9) return;
    int co = out % COUT;
    int r  = out / COUT;
    wT[out] = w[(long)co*(CIN*9) + r];
}

__global__ __launch_bounds__(256) void stats_old_kernel(const u16* __restrict__ m,
        float* __restrict__ mu_out, float* __restrict__ inv_out){
    int co = blockIdx.x;
    float s=0.f, s2=0.f;
    for (int oc = threadIdx.x; oc < NPIX/8; oc += 256){
        int b = oc / (HW/8); int o8 = oc - b*(HW/8);
        const s16x8 v8 = *(const s16x8*)&m[((size_t)(b*COUT+co))*HW + (size_t)o8*8];
        #pragma unroll
        for (int j=0;j<8;j++){ float v = b2f((u16)v8[j]); s += v; s2 += v*v; }
    }
    __shared__ float rs[256], rs2[256];
    rs[threadIdx.x]=s; rs2[threadIdx.x]=s2; __syncthreads();
    for (int o=128;o>0;o>>=1){
        if (threadIdx.x < o){ rs[threadIdx.x]+=rs[threadIdx.x+o]; rs2[threadIdx.x]+=rs2[threadIdx.x+o]; }
        __syncthreads();
    }
    if (threadIdx.x==0){
        float mu = rs[0]/(float)NPIX;
        float var = rs2[0]/(float)NPIX - mu*mu;
        mu_out[co] = mu;
        inv_out[co] = 1.0f/sqrtf(var + 1e-5f);
    }
}

__global__ __launch_bounds__(256) void final_old_kernel(
        const u16* __restrict__ m, const u16* __restrict__ var,
        const float* __restrict__ mu_, const float* __restrict__ inv_,
        const float* __restrict__ gamma, const float* __restrict__ beta,
        float* __restrict__ out){
    long idx = (long)blockIdx.x*256 + threadIdx.x;
    int wo = (int)(idx % PW); long t = idx / PW;
    int ho = (int)(t % PH); t /= PH;
    int co = (int)(t % COUT); int b = (int)(t / COUT);
    float g  = gamma[co];
    float be = beta[co];
    float mu = mu_[co], inv = inv_[co];
    float ag = fabsf(g);
    float us = 0.f, ss = 0.f;
    #pragma unroll
    for (int dh=0; dh<2; ++dh){
        int hpos = 2*ho+dh;
        long base = ((long)(b*COUT+co)*HH + hpos)*WW + 2*wo;
        #pragma unroll
        for (int dw=0; dw<2; ++dw){
            float mm = b2f(m[base+dw]);
            float vv = b2f(var[base+dw]);
            float sdev = sqrtf(vv + 1e-12f);
            float uhat = (mm - mu)*inv*g + be;
            float shat = sdev*inv*ag;
            float z = uhat / (shat*1.41421356237f + 1e-12f);
            float u = 0.5f*(1.f + erff(z));
            float sa2 = fmaxf(u*(1.f-u), 1e-12f);
            us += u; ss += sa2;
        }
    }
    out[idx]              = 0.25f*us;
    out[POOL_ELEMS + idx] = sqrtf(0.25f*ss)*0.5f;
}

#define CI_CHUNK 64
#define XW 32
__global__ __launch_bounds__(256) void conv_old_kernel(
    const float* __restrict__ mean, const float* __restrict__ stdv,
    const float* __restrict__ wT, const float* __restrict__ bias,
    u16* __restrict__ m_out, u16* __restrict__ v_out)
{
    __shared__ float lds_m[CI_CHUNK][3][XW];
    __shared__ float lds_s[CI_CHUNK][3][XW];
    const int co   = threadIdx.x;
    const int half = blockIdx.x;
    const int h    = blockIdx.y;
    const int b    = blockIdx.z;
    const int w_base = half*28;

    float acc_m[28], acc_v[28];
    #pragma unroll
    for (int i=0;i<28;i++){ acc_m[i]=0.f; acc_v[i]=0.f; }

    for (int c=0; c<CIN; c+=CI_CHUNK){
        for (int t = threadIdx.x; t < CI_CHUNK*3*30; t += 256){
            int pos = t % 30; int r = t / 30; int hh = r % 3; int ci_l = r / 3;
            int gh = h - 1 + hh; int gw = w_base - 1 + pos;
            float vm = 0.f, vs = 0.f;
            if ((unsigned)gh < (unsigned)HH && (unsigned)gw < (unsigned)WW){
                long gi = ((long)(b*CIN + (c+ci_l))*HH + gh)*WW + gw;
                vm = mean[gi];
                float sv = stdv[gi];
                vs = sv*sv;
            }
            lds_m[ci_l][hh][pos] = vm;
            lds_s[ci_l][hh][pos] = vs;
        }
        __syncthreads();
        for (int ci_l=0; ci_l<CI_CHUNK; ++ci_l){
            int rbase = (c+ci_l)*9;
            #pragma unroll
            for (int kh=0; kh<3; ++kh){
                float w0 = wT[(long)(rbase + kh*3 + 0)*COUT + co];
                float w1 = wT[(long)(rbase + kh*3 + 1)*COUT + co];
                float w2 = wT[(long)(rbase + kh*3 + 2)*COUT + co];
                float xm[30];
                #pragma unroll
                for (int p=0;p<30;p++) xm[p] = lds_m[ci_l][kh][p];
                #pragma unroll
                for (int i=0;i<28;i++) acc_m[i] += w0*xm[i] + w1*xm[i+1] + w2*xm[i+2];
                float q0=w0*w0, q1=w1*w1, q2=w2*w2;
                float xs[30];
                #pragma unroll
                for (int p=0;p<30;p++) xs[p] = lds_s[ci_l][kh][p];
                #pragma unroll
                for (int i=0;i<28;i++) acc_v[i] += q0*xs[i] + q1*xs[i+1] + q2*xs[i+2];
            }
        }
        __syncthreads();
    }
    float bvv = bias[co];
    long obase = ((long)(b*COUT+co)*HH + h)*WW + w_base;
    #pragma unroll
    for (int i=0;i<28;i++){
        m_out[obase+i] = f2b(acc_m[i]+bvv);
        v_out[obase+i] = f2b(acc_v[i]);
    }
}

// ================= launcher =================
extern "C" void kernel_launch(void* const* d_in, const int* in_sizes, int n_in,
                              void* d_out, int out_size, void* d_ws, size_t ws_size,
                              hipStream_t stream)
{
    const float* mean   = (const float*)d_in[0];
    const float* stdv   = (const float*)d_in[1];
    const float* conv_w = (const float*)d_in[2];
    const float* conv_b = (const float*)d_in[3];
    const float* gamma  = (const float*)d_in[4];
    const float* beta   = (const float*)d_in[5];
    float* out = (float*)d_out;
    char* ws = (char*)d_ws;

    // fast-path workspace layout (bytes)
    const size_t PAD_BYTES  = (size_t)BB*PADH*PADW*CIN*2;        // 27,549,696
    const size_t SLACK      = 8192;
    const size_t OFF_STD2   = PAD_BYTES + SLACK;
    const size_t OFF_WT     = OFF_STD2 + PAD_BYTES + SLACK;
    const size_t WT_BYTES   = (size_t)9*COUT*CIN*2;               // 589,824
    const size_t OFF_WT2    = OFF_WT + WT_BYTES;
    const size_t OFF_M      = OFF_WT2 + WT_BYTES;
    const size_t MV_BYTES   = (size_t)BB*COUT*HH*MSTRIDE*2;       // 58,720,256
    const size_t OFF_V      = OFF_M + MV_BYTES;
    const size_t OFF_SUM    = OFF_V + MV_BYTES;
    const size_t OFF_SUMSQ  = OFF_SUM + 1024;
    const size_t NEED_FAST  = OFF_SUMSQ + 1024;                   // ~176 MB

    if (ws_size >= NEED_FAST){
        u16* mean_pad = (u16*)ws;
        u16* std2_pad = (u16*)(ws + OFF_STD2);
        u16* BP   = (u16*)(ws + OFF_WT);
        u16* BP2  = (u16*)(ws + OFF_WT2);
        u16* m_buf = (u16*)(ws + OFF_M);
        u16* v_buf = (u16*)(ws + OFF_V);
        float* sum_   = (float*)(ws + OFF_SUM);
        float* sumsq_ = (float*)(ws + OFF_SUMSQ);

        prep_kernel<<<ROW_BLOCKS + TOPBOT_BLOCKS + WPACK_BLOCKS, 256, 0, stream>>>(
            mean, stdv, conv_w, mean_pad, std2_pad, BP, BP2, sum_, sumsq_);
        convw_kernel<<<(NPIX/112)*2, 512, 0, stream>>>(
            mean_pad, std2_pad, BP, BP2, conv_b, m_buf, v_buf, sum_, sumsq_);
        final_kernel<<<(int)(POOL_ELEMS/4/256), 256, 0, stream>>>(
            m_buf, v_buf, sum_, sumsq_, gamma, beta, out);
    } else {
        // fallback: round-2 structure with bf16 m/v
        u16* m_buf = (u16*)ws;
        u16* v_buf = (u16*)(ws + (size_t)BB*COUT*HW*2);
        float* wT  = (float*)(ws + (size_t)BB*COUT*HW*4);
        float* mu  = (float*)(ws + (size_t)BB*COUT*HW*4 + (size_t)COUT*CIN*9*4);
        float* inv = mu + 256;
        wtransf_kernel<<<(COUT*CIN*9+255)/256, 256, 0, stream>>>(conv_w, wT);
        conv_old_kernel<<<dim3(2, HH, BB), 256, 0, stream>>>(mean, stdv, wT, conv_b, m_buf, v_buf);
        stats_old_kernel<<<COUT, 256, 0, stream>>>(m_buf, mu, inv);
        final_old_kernel<<<(int)(POOL_ELEMS/256), 256, 0, stream>>>(m_buf, v_buf, mu, inv, gamma, beta, out);
    }
}

// Round 18
// 204.697 us; speedup vs baseline: 1.1699x; 1.1699x over previous
//
#include <hip/hip_runtime.h>
#include <hip/hip_bf16.h>
#include <math.h>

// ---------------- problem constants ----------------
#define BB 32
#define CIN 128
#define HH 56
#define WW 56
#define COUT 256
#define HW (HH*WW)              // 3136
#define NPIX (BB*HW)            // 100352
#define PH 28
#define PW 28
#define POOL_ELEMS ((long)BB*COUT*PH*PW) // 6,422,528
#define PADH 58
#define PADW 58
#define ROW_BLOCKS (BB*HH)                    // 1792 : one per (b,h) interior row
#define TOPBOT_BLOCKS (BB*2)                  // 64   : padded rows 0 and 57
#define WPACK_BLOCKS ((9*COUT*CIN)/256)       // 1152

typedef unsigned short u16;
using s16x8 = __attribute__((ext_vector_type(8))) short;
using s16x4 = __attribute__((ext_vector_type(4))) short;
using f32x4 = __attribute__((ext_vector_type(4))) float;

__device__ __forceinline__ float b2f(u16 u){ return __uint_as_float(((unsigned)u)<<16); }
__device__ __forceinline__ u16 f2b(float x){           // RNE f32->bf16
    unsigned u = __float_as_uint(x);
    unsigned r = (u + 0x7fffu + ((u>>16)&1u)) >> 16;
    return (u16)r;
}

__device__ __forceinline__ void gload16(const void* g, void* l){
    __builtin_amdgcn_global_load_lds(
        (const __attribute__((address_space(1))) unsigned int*)g,
        (__attribute__((address_space(3))) unsigned int*)l, 16, 0, 0);
}

// ================= FAST PATH =================

// prep: blocks [0,ROW_BLOCKS): one (b,h) row -- float4-coalesced NCHW loads,
//   LDS transpose, 256B-contiguous NHWC bf16 stores (mean, std^2) + halo cols.
// blocks [ROW_BLOCKS, +TOPBOT_BLOCKS): zero padded rows 0/57 (+ zero stats accum).
// blocks [.., +WPACK_BLOCKS): weight pack (BP idx = ((ks*4+sub)*256+co)*8+e).
__global__ __launch_bounds__(256) void prep_kernel(
    const float* __restrict__ mean, const float* __restrict__ stdv,
    const float* __restrict__ w,
    u16* __restrict__ mean_pad, u16* __restrict__ std2_pad,
    u16* __restrict__ BP, u16* __restrict__ BP2,
    float* __restrict__ sum_, float* __restrict__ sumsq_)
{
    const int bid = blockIdx.x;
    const int t   = threadIdx.x;

    if (bid < ROW_BLOCKS){
        // ---- transpose one interior row: 128 ch x 56 w, both inputs
        __shared__ u16 ldsm[56*128];
        __shared__ u16 ldss[56*128];
        const int b = bid / HH;
        const int h = bid - b*HH;

        // load: idx = k*256+t in [0,1792) = c*14 + f4 ; float4 along w
        #pragma unroll
        for (int k=0; k<7; ++k){
            int idx = k*256 + t;
            int c   = idx / 14;
            int f4  = idx - c*14;
            long ga = ((long)(b*CIN + c)*HH + h)*WW + f4*4;
            const f32x4 m4 = *(const f32x4*)(mean + ga);
            const f32x4 s4 = *(const f32x4*)(stdv + ga);
            #pragma unroll
            for (int j=0; j<4; ++j){
                int px = f4*4 + j;
                int ci = px*128 + (c ^ ((px & 15) << 3));   // col-XOR swizzle
                ldsm[ci] = f2b(m4[j]);
                ldss[ci] = f2b(s4[j] * s4[j]);
            }
        }
        __syncthreads();

        // store: 56 px x 16 oct, 16B per (px,oct); swizzle keeps 8 u16 contiguous
        const long rowbase = ((long)(b*PADH + (h+1)))*PADW*CIN;
        #pragma unroll
        for (int k=0; k<4; ++k){
            int slot = k*256 + t;          // 0..1023
            int px   = slot >> 4;
            int oct  = slot & 15;
            if (px < 56){
                int ci = px*128 + ((oct ^ (px & 15)) << 3);
                long o = rowbase + (long)(px+1)*CIN + oct*8;
                *(s16x8*)(mean_pad + o) = *(const s16x8*)&ldsm[ci];
                *(s16x8*)(std2_pad + o) = *(const s16x8*)&ldss[ci];
            }
        }
        // halo cols 0 and 57 of this padded row
        if (t < 64){
            int buf = t >> 5;              // 0: mean, 1: std2
            int ppx = ((t >> 4) & 1) ? 57 : 0;
            int oct = t & 15;
            long o  = rowbase + (long)ppx*CIN + oct*8;
            s16x8 z = (s16x8){0,0,0,0,0,0,0,0};
            *(s16x8*)((buf ? std2_pad : mean_pad) + o) = z;
        }
    } else if (bid < ROW_BLOCKS + TOPBOT_BLOCKS){
        // ---- zero padded rows 0 / 57 (both buffers); block 0 also zeroes stats
        int row = bid - ROW_BLOCKS;        // 0..63
        int b   = row >> 1;
        int ph  = (row & 1) ? (PADH-1) : 0;
        const long rowbase = ((long)(b*PADH + ph))*PADW*CIN;
        s16x8 z = (s16x8){0,0,0,0,0,0,0,0};
        #pragma unroll
        for (int k=0; k<8; ++k){
            int g = k*256 + t;             // 0..2047 ; need 1856
            if (g < 2*PADW*16){
                int buf = g >= PADW*16;
                int gg  = buf ? g - PADW*16 : g;
                int px  = gg >> 4;
                int oct = gg & 15;
                long o  = rowbase + (long)px*CIN + oct*8;
                *(s16x8*)((buf ? std2_pad : mean_pad) + o) = z;
            }
        }
        if (row == 0){ sum_[t] = 0.f; sumsq_[t] = 0.f; }
    } else {
        // ---- weight pack
        int tt = (bid - ROW_BLOCKS - TOPBOT_BLOCKS)*256 + t;   // 0..294911
        int e    = tt & 7;
        int co   = (tt >> 3) & 255;
        int rest = tt >> 11;
        int ks   = rest >> 2;
        int sub  = rest & 3;
        int r    = ks >> 2;
        int ci   = (ks & 3)*32 + sub*8 + e;
        float v = w[((long)co*CIN + ci)*9 + r];
        BP[tt]  = f2b(v);
        BP2[tt] = f2b(v*v);
    }
}

// implicit-GEMM conv via MFMA -- TAP-REUSE WINDOW staging, WIDE wave tile
// (r13 kernel: 4-bit both-sides XOR swizzle + setprio around MFMA).
// Block = 112 pixels (2 output rows x 56 cols) x 256 co, one path; 4 waves,
// each 112 pix x 64 co (7 mi x 4 ni). Window (4 padded rows x 64 cols x 128 ci
// = 64KB) staged ONCE; k-loop has zero barriers/drains. B frags from packed
// global (L2) into registers.
// LDS layout: [R=256 rows (pr*64+col)][16 slots x 16B]; LDS[R][s] holds global
// ci-quad s ^ (R&15); write-side source quad (t&15)^((t>>4)&15)  [rule #21].
__global__ __launch_bounds__(256,2) void convw_kernel(
    const u16* __restrict__ mean_pad, const u16* __restrict__ std2_pad,
    const u16* __restrict__ BP, const u16* __restrict__ BP2,
    const float* __restrict__ bias,
    u16* __restrict__ m_out, u16* __restrict__ v_out,
    float* __restrict__ sum_, float* __restrict__ sumsq_)
{
    __shared__ u16 lds[32768];   // 64KB: [256][16 x 16B]
    const int tid  = threadIdx.x;
    const int lane = tid & 63;
    const int wv   = tid >> 6;

    // XCD-affine decode: 1792 blocks = 8 XCDs x 224; per XCD 112 p-tiles x 2 paths.
    int gid   = blockIdx.x;
    int local = gid >> 3;                       // 0..223
    int p     = (gid & 7)*112 + (local >> 1);   // 0..895
    int path  = local & 1;
    const int b  = p / 28;
    const int h0 = (p - b*28) * 2;              // first output row (even)

    const u16* __restrict__ Ap = path ? std2_pad : mean_pad;
    const u16* __restrict__ Bp = path ? BP2      : BP;
    u16*       __restrict__ Op = path ? v_out    : m_out;

    // ---- stage window: padded rows h0..h0+3, cols 0..63 (58..63 slack), 128 ci
    const int slot_g = (tid & 15) ^ ((tid >> 4) & 15);
    const int wbase  = (b*PADH + h0)*PADW*CIN;
    const int athr   = (tid >> 4)*CIN + slot_g*8;
    #pragma unroll
    for (int i=0; i<16; ++i){
        const int Ci = (i>>2)*(PADW*CIN) + (i&3)*16*CIN;
        gload16(Ap + wbase + Ci + athr, &lds[i*2048 + tid*8]);
    }
    __syncthreads();   // single drain for the whole block

    // ---- per-lane fragment constants
    int R0[7];
    #pragma unroll
    for (int mi=0; mi<7; ++mi){
        int px = mi*16 + (lane & 15);
        int dh = (px >= 56) ? 1 : 0;
        R0[mi] = dh*64 + (px - dh*56);
    }
    const int q = lane >> 4;   // logical ci quad (bits 0-1 of 4-bit slot index)

    const u16* bp = Bp + (size_t)((lane>>4)*256 + wv*64 + (lane&15))*8;

    f32x4 acc[7][4];
    #pragma unroll
    for (int i=0;i<7;i++)
      #pragma unroll
      for (int j=0;j<4;j++) acc[i][j] = (f32x4){0,0,0,0};

    #pragma unroll
    for (int r=0; r<9; ++r){
        const int kh = r/3, kw = r - (r/3)*3;

        // A base addresses for this tap (kk0, hf0); kk -> ^32, hf -> ^64
        int ab[7];
        #pragma unroll
        for (int mi=0; mi<7; ++mi){
            int R   = R0[mi] + kh*64 + kw;
            int t15 = (R0[mi] + kw) & 15;        // == R&15 (kh*64 % 16 == 0)
            ab[mi] = R*128 + ((q ^ t15) << 3);
        }

        #pragma unroll
        for (int hf=0; hf<2; ++hf){
            #pragma unroll
            for (int kk=0; kk<2; ++kk){
                const size_t ksoff = (size_t)(r*4 + hf*2 + kk)*8192;
                s16x8 bf0 = *(const s16x8*)(bp + ksoff);
                s16x8 bf1 = *(const s16x8*)(bp + ksoff + 128);
                s16x8 bf2 = *(const s16x8*)(bp + ksoff + 256);
                s16x8 bf3 = *(const s16x8*)(bp + ksoff + 384);
                const int sx = hf*64 + kk*32;    // pure XOR on slot bits 3..2
                s16x8 af[7];
                #pragma unroll
                for (int mi=0; mi<7; ++mi)
                    af[mi] = *(const s16x8*)&lds[ab[mi] ^ sx];
                __builtin_amdgcn_s_setprio(1);
                #pragma unroll
                for (int mi=0; mi<7; ++mi){
                    acc[mi][0] = __builtin_amdgcn_mfma_f32_16x16x32_bf16(af[mi], bf0, acc[mi][0], 0,0,0);
                    acc[mi][1] = __builtin_amdgcn_mfma_f32_16x16x32_bf16(af[mi], bf1, acc[mi][1], 0,0,0);
                    acc[mi][2] = __builtin_amdgcn_mfma_f32_16x16x32_bf16(af[mi], bf2, acc[mi][2], 0,0,0);
                    acc[mi][3] = __builtin_amdgcn_mfma_f32_16x16x32_bf16(af[mi], bf3, acc[mi][3], 0,0,0);
                }
                __builtin_amdgcn_s_setprio(0);
            }
        }
    }

    // ---- epilogue. D-frag: col=lane&15 (co), row=(lane>>4)*4+reg (pixel).
    float bv[4];
    if (path == 0){
        #pragma unroll
        for (int ni=0;ni<4;ni++) bv[ni] = bias[wv*64 + ni*16 + (lane&15)];
    } else {
        #pragma unroll
        for (int ni=0;ni<4;ni++) bv[ni] = 0.f;
    }

    float ssum[4] = {0.f,0.f,0.f,0.f}, ssq[4] = {0.f,0.f,0.f,0.f};

    #pragma unroll
    for (int mi=0; mi<7; ++mi){
        int px = mi*16 + ((lane>>4)<<2);
        int dh = (px >= 56) ? 1 : 0;
        int w  = px - dh*56;
        #pragma unroll
        for (int ni=0; ni<4; ++ni){
            int co = wv*64 + ni*16 + (lane&15);
            size_t o = (size_t)(b*COUT + co)*HW + (size_t)(h0+dh)*WW + w;
            s16x4 pk;
            #pragma unroll
            for (int rr=0; rr<4; ++rr){
                float vv = acc[mi][ni][rr] + bv[ni];
                pk[rr] = (short)f2b(vv);
                ssum[ni] += vv;
                ssq[ni]  += vv*vv;
            }
            *(s16x4*)(Op + o) = pk;
        }
    }

    if (path == 0){
        #pragma unroll
        for (int ni=0; ni<4; ++ni){
            float s = ssum[ni], s2 = ssq[ni];
            s  += __shfl_xor(s, 16, 64);  s2 += __shfl_xor(s2, 16, 64);
            s  += __shfl_xor(s, 32, 64);  s2 += __shfl_xor(s2, 32, 64);
            if (lane < 16){
                int co = wv*64 + ni*16 + lane;
                atomicAdd(&sum_[co],   s);
                atomicAdd(&sumsq_[co], s2);
            }
        }
    }
}

// BN + erf + 2x2 pool -> f32 outputs; mu/inv computed inline from atomic partials.
__global__ __launch_bounds__(256) void final_kernel(
        const u16* __restrict__ m, const u16* __restrict__ var,
        const float* __restrict__ sum_, const float* __restrict__ sumsq_,
        const float* __restrict__ gamma, const float* __restrict__ beta,
        float* __restrict__ out){
    int idx4 = blockIdx.x*256 + threadIdx.x;   // < POOL_ELEMS/4
    int wo4 = idx4 % (PW/4); int t = idx4 / (PW/4);
    int ho = t % PH; t /= PH;
    int co = t % COUT; int b = t / COUT;
    float g  = gamma[co];
    float be = beta[co];
    float mu = sum_[co] / (float)NPIX;
    float vr = sumsq_[co] / (float)NPIX - mu*mu;
    float inv = 1.0f / sqrtf(vr + 1e-5f);
    float ag = fabsf(g);
    float us[4] = {0.f,0.f,0.f,0.f}, ss[4] = {0.f,0.f,0.f,0.f};
    #pragma unroll
    for (int dh=0; dh<2; ++dh){
        long base = ((long)(b*COUT+co)*HH + 2*ho+dh)*WW + wo4*8;
        const s16x8 vm = *(const s16x8*)&m[base];
        const s16x8 vv = *(const s16x8*)&var[base];
        #pragma unroll
        for (int j=0;j<8;j++){
            float mm = b2f((u16)vm[j]);
            float sdev = sqrtf(b2f((u16)vv[j]) + 1e-12f);
            float uhat = (mm - mu)*inv*g + be;
            float shat = sdev*inv*ag;
            float z = uhat / (shat*1.41421356237f + 1e-12f);
            float u = 0.5f*(1.f + erff(z));
            us[j>>1] += u;
            ss[j>>1] += fmaxf(u*(1.f-u), 1e-12f);
        }
    }
    long ob = ((long)(b*COUT+co)*PH + ho)*PW + wo4*4;
    f32x4 o0, o1;
    #pragma unroll
    for (int k=0;k<4;k++){
        o0[k] = 0.25f*us[k];
        o1[k] = sqrtf(0.25f*ss[k])*0.5f;
    }
    *(f32x4*)(out + ob) = o0;
    *(f32x4*)(out + POOL_ELEMS + ob) = o1;
}

// ================= FALLBACK PATH (round-2 VALU conv, bf16 m/v out) =================

__global__ void wtransf_kernel(const float* __restrict__ w, float* __restrict__ wT){
    int out = blockIdx.x*256 + threadIdx.x;
    if (out >= COUT*CIN*9) return;
    int co = out % COUT;
    int r  = out / COUT;
    wT[out] = w[(long)co*(CIN*9) + r];
}

__global__ __launch_bounds__(256) void stats_old_kernel(const u16* __restrict__ m,
        float* __restrict__ mu_out, float* __restrict__ inv_out){
    int co = blockIdx.x;
    float s=0.f, s2=0.f;
    for (int oc = threadIdx.x; oc < NPIX/8; oc += 256){
        int b = oc / (HW/8); int o8 = oc - b*(HW/8);
        const s16x8 v8 = *(const s16x8*)&m[((size_t)(b*COUT+co))*HW + (size_t)o8*8];
        #pragma unroll
        for (int j=0;j<8;j++){ float v = b2f((u16)v8[j]); s += v; s2 += v*v; }
    }
    __shared__ float rs[256], rs2[256];
    rs[threadIdx.x]=s; rs2[threadIdx.x]=s2; __syncthreads();
    for (int o=128;o>0;o>>=1){
        if (threadIdx.x < o){ rs[threadIdx.x]+=rs[threadIdx.x+o]; rs2[threadIdx.x]+=rs2[threadIdx.x+o]; }
        __syncthreads();
    }
    if (threadIdx.x==0){
        float mu = rs[0]/(float)NPIX;
        float var = rs2[0]/(float)NPIX - mu*mu;
        mu_out[co] = mu;
        inv_out[co] = 1.0f/sqrtf(var + 1e-5f);
    }
}

__global__ __launch_bounds__(256) void final_old_kernel(
        const u16* __restrict__ m, const u16* __restrict__ var,
        const float* __restrict__ mu_, const float* __restrict__ inv_,
        const float* __restrict__ gamma, const float* __restrict__ beta,
        float* __restrict__ out){
    long idx = (long)blockIdx.x*256 + threadIdx.x;
    int wo = (int)(idx % PW); long t = idx / PW;
    int ho = (int)(t % PH); t /= PH;
    int co = (int)(t % COUT); int b = (int)(t / COUT);
    float g  = gamma[co];
    float be = beta[co];
    float mu = mu_[co], inv = inv_[co];
    float ag = fabsf(g);
    float us = 0.f, ss = 0.f;
    #pragma unroll
    for (int dh=0; dh<2; ++dh){
        int hpos = 2*ho+dh;
        long base = ((long)(b*COUT+co)*HH + hpos)*WW + 2*wo;
        #pragma unroll
        for (int dw=0; dw<2; ++dw){
            float mm = b2f(m[base+dw]);
            float vv = b2f(var[base+dw]);
            float sdev = sqrtf(vv + 1e-12f);
            float uhat = (mm - mu)*inv*g + be;
            float shat = sdev*inv*ag;
            float z = uhat / (shat*1.41421356237f + 1e-12f);
            float u = 0.5f*(1.f + erff(z));
            float sa2 = fmaxf(u*(1.f-u), 1e-12f);
            us += u; ss += sa2;
        }
    }
    out[idx]              = 0.25f*us;
    out[POOL_ELEMS + idx] = sqrtf(0.25f*ss)*0.5f;
}

#define CI_CHUNK 64
#define XW 32
__global__ __launch_bounds__(256) void conv_old_kernel(
    const float* __restrict__ mean, const float* __restrict__ stdv,
    const float* __restrict__ wT, const float* __restrict__ bias,
    u16* __restrict__ m_out, u16* __restrict__ v_out)
{
    __shared__ float lds_m[CI_CHUNK][3][XW];
    __shared__ float lds_s[CI_CHUNK][3][XW];
    const int co   = threadIdx.x;
    const int half = blockIdx.x;
    const int h    = blockIdx.y;
    const int b    = blockIdx.z;
    const int w_base = half*28;

    float acc_m[28], acc_v[28];
    #pragma unroll
    for (int i=0;i<28;i++){ acc_m[i]=0.f; acc_v[i]=0.f; }

    for (int c=0; c<CIN; c+=CI_CHUNK){
        for (int t = threadIdx.x; t < CI_CHUNK*3*30; t += 256){
            int pos = t % 30; int r = t / 30; int hh = r % 3; int ci_l = r / 3;
            int gh = h - 1 + hh; int gw = w_base - 1 + pos;
            float vm = 0.f, vs = 0.f;
            if ((unsigned)gh < (unsigned)HH && (unsigned)gw < (unsigned)WW){
                long gi = ((long)(b*CIN + (c+ci_l))*HH + gh)*WW + gw;
                vm = mean[gi];
                float sv = stdv[gi];
                vs = sv*sv;
            }
            lds_m[ci_l][hh][pos] = vm;
            lds_s[ci_l][hh][pos] = vs;
        }
        __syncthreads();
        for (int ci_l=0; ci_l<CI_CHUNK; ++ci_l){
            int rbase = (c+ci_l)*9;
            #pragma unroll
            for (int kh=0; kh<3; ++kh){
                float w0 = wT[(long)(rbase + kh*3 + 0)*COUT + co];
                float w1 = wT[(long)(rbase + kh*3 + 1)*COUT + co];
                float w2 = wT[(long)(rbase + kh*3 + 2)*COUT + co];
                float xm[30];
                #pragma unroll
                for (int p=0;p<30;p++) xm[p] = lds_m[ci_l][kh][p];
                #pragma unroll
                for (int i=0;i<28;i++) acc_m[i] += w0*xm[i] + w1*xm[i+1] + w2*xm[i+2];
                float q0=w0*w0, q1=w1*w1, q2=w2*w2;
                float xs[30];
                #pragma unroll
                for (int p=0;p<30;p++) xs[p] = lds_s[ci_l][kh][p];
                #pragma unroll
                for (int i=0;i<28;i++) acc_v[i] += q0*xs[i] + q1*xs[i+1] + q2*xs[i+2];
            }
        }
        __syncthreads();
    }
    float bvv = bias[co];
    long obase = ((long)(b*COUT+co)*HH + h)*WW + w_base;
    #pragma unroll
    for (int i=0;i<28;i++){
        m_out[obase+i] = f2b(acc_m[i]+bvv);
        v_out[obase+i] = f2b(acc_v[i]);
    }
}

// ================= launcher =================
extern "C" void kernel_launch(void* const* d_in, const int* in_sizes, int n_in,
                              void* d_out, int out_size, void* d_ws, size_t ws_size,
                              hipStream_t stream)
{
    const float* mean   = (const float*)d_in[0];
    const float* stdv   = (const float*)d_in[1];
    const float* conv_w = (const float*)d_in[2];
    const float* conv_b = (const float*)d_in[3];
    const float* gamma  = (const float*)d_in[4];
    const float* beta   = (const float*)d_in[5];
    float* out = (float*)d_out;
    char* ws = (char*)d_ws;

    // fast-path workspace layout (bytes); 8KB slack after each pad buffer for
    // the staging over-read of the col 58..63 pad at the last rows.
    const size_t PAD_BYTES  = (size_t)BB*PADH*PADW*CIN*2;        // 27,549,696
    const size_t SLACK      = 8192;
    const size_t OFF_STD2   = PAD_BYTES + SLACK;
    const size_t OFF_WT     = OFF_STD2 + PAD_BYTES + SLACK;
    const size_t WT_BYTES   = (size_t)9*COUT*CIN*2;               // 589,824
    const size_t OFF_WT2    = OFF_WT + WT_BYTES;
    const size_t OFF_M      = OFF_WT2 + WT_BYTES;
    const size_t MV_BYTES   = (size_t)BB*COUT*HW*2;               // 51,380,224
    const size_t OFF_V      = OFF_M + MV_BYTES;
    const size_t OFF_SUM    = OFF_V + MV_BYTES;
    const size_t OFF_SUMSQ  = OFF_SUM + 1024;
    const size_t NEED_FAST  = OFF_SUMSQ + 1024;

    if (ws_size >= NEED_FAST){
        u16* mean_pad = (u16*)ws;
        u16* std2_pad = (u16*)(ws + OFF_STD2);
        u16* BP   = (u16*)(ws + OFF_WT);
        u16* BP2  = (u16*)(ws + OFF_WT2);
        u16* m_buf = (u16*)(ws + OFF_M);
        u16* v_buf = (u16*)(ws + OFF_V);
        float* sum_   = (float*)(ws + OFF_SUM);
        float* sumsq_ = (float*)(ws + OFF_SUMSQ);

        prep_kernel<<<ROW_BLOCKS + TOPBOT_BLOCKS + WPACK_BLOCKS, 256, 0, stream>>>(
            mean, stdv, conv_w, mean_pad, std2_pad, BP, BP2, sum_, sumsq_);
        convw_kernel<<<(NPIX/112)*2, 256, 0, stream>>>(
            mean_pad, std2_pad, BP, BP2, conv_b, m_buf, v_buf, sum_, sumsq_);
        final_kernel<<<(int)(POOL_ELEMS/4/256), 256, 0, stream>>>(
            m_buf, v_buf, sum_, sumsq_, gamma, beta, out);
    } else {
        // fallback: round-2 structure with bf16 m/v
        u16* m_buf = (u16*)ws;
        u16* v_buf = (u16*)(ws + (size_t)BB*COUT*HW*2);
        float* wT  = (float*)(ws + (size_t)BB*COUT*HW*4);
        float* mu  = (float*)(ws + (size_t)BB*COUT*HW*4 + (size_t)COUT*CIN*9*4);
        float* inv = mu + 256;
        wtransf_kernel<<<(COUT*CIN*9+255)/256, 256, 0, stream>>>(conv_w, wT);
        conv_old_kernel<<<dim3(2, HH, BB), 256, 0, stream>>>(mean, stdv, wT, conv_b, m_buf, v_buf);
        stats_old_kernel<<<COUT, 256, 0, stream>>>(m_buf, mu, inv);
        final_old_kernel<<<(int)(POOL_ELEMS/256), 256, 0, stream>>>(m_buf, v_buf, mu, inv, gamma, beta, out);
    }
}